// Round 7
// baseline (602.626 us; speedup 1.0000x reference)
//
#include <hip/hip_runtime.h>
#include <math.h>

#define S 4
#define G 3
#define NN 20000
#define EE 320000
#define D 64
#define SG (S*G)

#define RGS 32           // dst-ranges per graph
#define RNODES2 625      // NN / RGS
#define BCAP 14336       // bucket capacity per (sg,range); mean 10000 + pad(<=3/node)
#define CHUNKA 100       // edge chunks per sg in binA; 320000/100 = 3200 edges/block

#define NGRP   (NN/16)       // 1250 sorted 16-row groups per sg
// layer: one wave-task per 64-thread block. 12 sg x 1252 (1250 + 2 pad) = 15024 = 8 x 1878
#define LT2    15024
#define LT2PX  1878
#define GPAD   1252

static __device__ __forceinline__ float rcpf(float x){ return __builtin_amdgcn_rcpf(x); }
static __device__ __forceinline__ float sigmf(float x){ return rcpf(1.0f + __expf(-x)); }
static __device__ __forceinline__ float tanhf_fast(float x){
    float t = __expf(2.0f*x);
    return 1.0f - 2.0f*rcpf(t + 1.0f);
}

// float -> bf16 bits, round-nearest-even
static __device__ __forceinline__ unsigned short f2bf(float f){
    union { float f; unsigned u; } v; v.f = f;
    unsigned r = v.u + 0x7FFF + ((v.u >> 16) & 1);
    return (unsigned short)(r >> 16);
}

typedef short bf16x8 __attribute__((ext_vector_type(8)));
typedef float f32x4  __attribute__((ext_vector_type(4)));

// ---------------- Phase A: bin edges into 32 dst-range buckets, packed (dstLoc<<15)|src ----------------

__global__ __launch_bounds__(256) void binA_kernel(const int* __restrict__ ei,
                                                   int* __restrict__ bcur,
                                                   int* __restrict__ bkt){
    __shared__ int wcnt[4*RGS];
    __shared__ int wb[4*RGS];
    int chunk = blockIdx.x, sg = blockIdx.y;
    int tid = threadIdx.x, w = tid >> 6;
    const int* srcp = ei + (size_t)(sg*2 + 0)*EE;
    const int* dstp = ei + (size_t)(sg*2 + 1)*EE;
    const int EPC = EE/CHUNKA;               // 3200
    int start = chunk*EPC, end = start + EPC;

    for (int it = 0; it < (EPC + 1023)/1024; ++it){
        if (tid < 4*RGS) wcnt[tid] = 0;
        __syncthreads();
        int e = start + it*1024 + tid*4;
        bool valid = e < end;
        int d_[4], s_[4], r_[4], dl_[4], rk_[4];
        if (valid){
            int4 d4 = *(const int4*)&dstp[e];
            int4 s4 = *(const int4*)&srcp[e];
            d_[0]=d4.x; d_[1]=d4.y; d_[2]=d4.z; d_[3]=d4.w;
            s_[0]=s4.x; s_[1]=s4.y; s_[2]=s4.z; s_[3]=s4.w;
            #pragma unroll
            for (int j = 0; j < 4; ++j){
                int r = d_[j] / RNODES2;
                r_[j]  = r;
                dl_[j] = d_[j] - r*RNODES2;
                rk_[j] = atomicAdd(&wcnt[w*RGS + r], 1);
            }
        }
        __syncthreads();
        if (tid < RGS){
            int c0 = wcnt[0*RGS+tid], c1 = wcnt[1*RGS+tid];
            int c2 = wcnt[2*RGS+tid], c3 = wcnt[3*RGS+tid];
            int tot = c0+c1+c2+c3;
            int gb = 0;
            if (tot > 0) gb = atomicAdd(&bcur[sg*RGS + tid], tot);
            wb[0*RGS+tid] = gb;
            wb[1*RGS+tid] = gb + c0;
            wb[2*RGS+tid] = gb + c0 + c1;
            wb[3*RGS+tid] = gb + c0 + c1 + c2;
        }
        __syncthreads();
        if (valid){
            #pragma unroll
            for (int j = 0; j < 4; ++j){
                int pos = wb[w*RGS + r_[j]] + rk_[j];
                if (pos < BCAP)
                    bkt[(size_t)(sg*RGS + r_[j])*BCAP + pos] = (dl_[j] << 15) | s_[j];
            }
        }
    }
}

// ---------------- Phase B: per (sg,range): hist -> padded scan -> degree-sort -> CSR segment ----------------

__global__ __launch_bounds__(256) void buildB_kernel(int* __restrict__ bkt,
                                                     const int* __restrict__ bcur,
                                                     int* __restrict__ off2,
                                                     int* __restrict__ deg2,
                                                     int* __restrict__ nid2,
                                                     int* __restrict__ offU){
    __shared__ int hist[RNODES2];      // degree per node
    __shared__ int pref[RNODES2];      // CSR scatter cursor
    __shared__ int seg[BCAP];          // 57.3 KB
    __shared__ int sums[256];
    __shared__ int dh[64];             // degree histogram / sort cursor
    int sg = blockIdx.x / RGS, rg = blockIdx.x % RGS;
    int tid = threadIdx.x;
    int cnt = bcur[sg*RGS + rg];
    if (cnt > BCAP) cnt = BCAP;
    size_t base = (size_t)(sg*RGS + rg)*BCAP;
    int gnode = sg*NN + rg*RNODES2;

    for (int i = tid; i < RNODES2; i += 256) hist[i] = 0;
    if (tid < 64) dh[tid] = 0;
    __syncthreads();
    for (int j = tid; j < cnt; j += 256)
        atomicAdd(&hist[bkt[base + j] >> 15], 1);
    __syncthreads();

    int lo = tid*3, hi = min(lo+3, RNODES2);
    int s = 0;
    for (int i = lo; i < hi; ++i) s += (hist[i] + 3) & ~3;   // padded sizes
    sums[tid] = s; __syncthreads();
    for (int ofs = 1; ofs < 256; ofs <<= 1){
        int v = (tid >= ofs) ? sums[tid-ofs] : 0;
        __syncthreads();
        sums[tid] += v;
        __syncthreads();
    }
    int run = sums[tid] - s;
    for (int i = lo; i < hi; ++i){
        pref[i] = run;                       // CSR cursor (mutated below)
        offU[gnode + i] = (int)base + run;   // unsorted offset (read back in sort)
        run += (hist[i] + 3) & ~3;
    }
    __syncthreads();

    // degree histogram -> prefix -> sorted scatter of (off,deg,nid)
    for (int i = tid; i < RNODES2; i += 256)
        atomicAdd(&dh[min(hist[i], 63)], 1);
    __syncthreads();
    if (tid == 0){
        int r = 0;
        for (int k = 0; k < 64; ++k){ int c = dh[k]; dh[k] = r; r += c; }
    }
    __syncthreads();
    for (int i = tid; i < RNODES2; i += 256){
        int pos = atomicAdd(&dh[min(hist[i], 63)], 1);
        off2[gnode + pos] = offU[gnode + i];
        deg2[gnode + pos] = hist[i];
        nid2[gnode + pos] = rg*RNODES2 + i;
    }
    __syncthreads();

    for (int j = tid; j < cnt; j += 256){
        int p = bkt[base + j];
        int slot = atomicAdd(&pref[p >> 15], 1);
        if (slot < BCAP) seg[slot] = p & 0x7FFF;
    }
    __syncthreads();

    int padtot = min(sums[255], BCAP);
    for (int j = tid; j < padtot; j += 256) bkt[base + j] = seg[j];
}

// ---------------- x -> bf16 convert ----------------

__global__ __launch_bounds__(256) void convert_kernel(const float* __restrict__ x,
                                                      unsigned short* __restrict__ xb){
    int idx = blockIdx.x*256 + threadIdx.x;
    if (idx >= SG*NN*16) return;
    float4 v = ((const float4*)x)[idx];
    uint2 pk;
    pk.x = (unsigned)f2bf(v.x) | ((unsigned)f2bf(v.y) << 16);
    pk.y = (unsigned)f2bf(v.z) | ((unsigned)f2bf(v.w) << 16);
    ((uint2*)xb)[idx] = pk;
}

// ---------------- weight prep: all bf16, [col][k] layouts ----------------

__global__ __launch_bounds__(256) void wprep2_kernel(const float* __restrict__ W1l,
                                                     const float* __restrict__ W1r,
                                                     const float* __restrict__ W2l,
                                                     const float* __restrict__ W2r,
                                                     const float* __restrict__ Wih,
                                                     const float* __restrict__ Whh,
                                                     const float* __restrict__ bih,
                                                     const float* __restrict__ bhh,
                                                     unsigned short* __restrict__ WL1,
                                                     unsigned short* __restrict__ WL2,
                                                     unsigned short* __restrict__ Wt,
                                                     float* __restrict__ bc){
    int idx = blockIdx.x*256 + threadIdx.x;
    if (idx < 24576){
        int g = idx >> 13, rem = idx & 8191, col = rem >> 7, k = rem & 127;
        float v = (k < 64) ? W1l[((size_t)g*64 + k)*64 + col]
                           : W1r[((size_t)g*64 + (k-64))*64 + col];
        WL1[idx] = f2bf(v);
    } else if (idx < 49152){
        int t = idx - 24576;
        int g = t >> 13, rem = t & 8191, col = rem >> 7, k = rem & 127;
        float v = (k < 64) ? W2l[((size_t)g*64 + k)*64 + col]
                           : W2r[((size_t)g*64 + (k-64))*64 + col];
        WL2[t] = f2bf(v);
    } else if (idx < 81920){
        int t = idx - 49152;
        int col = t >> 7, k = t & 127;
        float v = (k < 64) ? Wih[col*64 + k] : Whh[col*64 + (k - 64)];
        Wt[t] = f2bf(v);
    } else if (idx < 82176){
        int t = idx - 81920;
        bc[t] = bih[t] + bhh[t];
    }
}

// ---------------- SAGE layer: identity-B MFMA segment-sum, 1-wave blocks,
// 32-edge chunks with register-level depth-2 pipeline + csr prefetch.
// Round-6 failure mode: both pipes idle at 33% occupancy, depth-1 per wave ->
// latency naked. This version: 4KB LDS/block (occupancy cap 62%) and two
// named gather register sets so each chunk's loads fly ~1.5 iterations. ----------------

#define WP 72
#define SWZ(e) ((((e) >> 1) ^ ((e) >> 4)) & 7)

// csr index prefetch for chunk CC (all 64 lanes; lanes>=32 duplicate lanes 0..31's
// addresses -> merged in TA, no extra traffic)
#define LDIX(IX, CC) { IX = csr[aG2 + (CC)*2 + (lane & 1)]; }

// issue the 4 coalesced gathers for chunk CC into register set V (edge = addr-lane,
// row = lane>>1, slot parity = lane&1; instruction j: 8 rows x 8 lanes x 16B)
#define GATH(V, IX, CC) { \
    int sL_ = (CC)*2 + (lane & 1); \
    unsigned adr_ = (sL_ < dgG2) ? (((unsigned)(IX)) << 7) : zoff0; \
    _Pragma("unroll") \
    for (int j_ = 0; j_ < 4; ++j_){ \
        unsigned ae_ = (unsigned)__shfl((int)adr_, j_*8 + (lane >> 3)); \
        V[j_] = *(const uint4*)(inbc + ae_ + (unsigned)((lane & 7) << 4)); \
    } \
}

// stage set V to LDS (swizzled) and run the 4 identity-B MFMAs
#define CONSUME(V) { \
    _Pragma("unroll") \
    for (int j_ = 0; j_ < 4; ++j_){ \
        int e_ = j_*8 + (lane >> 3); \
        int gr_ = ((lane & 7) ^ SWZ(e_)) << 4; \
        *(uint4*)((char*)stg + e_*128 + gr_) = V[j_]; \
    } \
    { \
        int e_ = r*2 + (q >> 1); \
        int eb_ = e_*128, sw_ = SWZ(e_) << 4; \
        _Pragma("unroll") \
        for (int cb_ = 0; cb_ < 4; ++cb_){ \
            int b_ = cb_*32 + ((q & 1) << 4); \
            bf16x8 af_ = *(const bf16x8*)((const char*)stg + eb_ + (b_ ^ sw_)); \
            acc[cb_] = __builtin_amdgcn_mfma_f32_16x16x32_bf16(af_, BI, acc[cb_], 0, 0, 0); \
        } \
    } \
}

__global__ __launch_bounds__(64) void layer_kernel(const unsigned short* __restrict__ xb,
                                                   const int* __restrict__ off2,
                                                   const int* __restrict__ deg2,
                                                   const int* __restrict__ nid2,
                                                   const int* __restrict__ csr,
                                                   const unsigned short* __restrict__ WL,
                                                   const float* __restrict__ bias,
                                                   unsigned short* __restrict__ outb){
    // 4KB: 32 edges x 128B stage; shorts [0,1152) reused as sM then sO (same wave,
    // in-order LDS -> no barriers anywhere in this kernel)
    __shared__ unsigned short stg[2048];
    int L = blockIdx.x;
    int task = (L & 7)*LT2PX + (L >> 3);      // bijective XCD swizzle (15024 = 8x1878)
    int sg = task / GPAD;
    int g0 = task - sg*GPAD;
    int gid = (GPAD - 1) - g0;                // high-degree groups first; 1250,1251 = pads
    if (gid >= NGRP) return;
    int g = sg % G;
    int lane = threadIdx.x;
    int r = lane & 15, q = lane >> 4;
    const char* inbc = (const char*)(xb + (size_t)sg*NN*D);

    // identity-B fragment: B[k][col]=1 iff (k&15)==col (rounds 5/6 hardware-verified)
    union { uint4 u; bf16x8 v; } biu;
    {
        unsigned v_ = 0x3F80u << ((r & 1) * 16);
        bool on = ((r >> 3) == (q & 1));
        int w_ = (r & 7) >> 1;
        biu.u.x = (on && w_ == 0) ? v_ : 0u;
        biu.u.y = (on && w_ == 1) ? v_ : 0u;
        biu.u.z = (on && w_ == 2) ? v_ : 0u;
        biu.u.w = (on && w_ == 3) ? v_ : 0u;
    }
    bf16x8 BI = biu.v;

    int idx = sg*NN + gid*16 + r;
    int node = nid2[idx];
    int a    = off2[idx];
    int dg   = deg2[idx];
    int mx = dg;
    mx = max(mx, __shfl_xor(mx, 1));
    mx = max(mx, __shfl_xor(mx, 2));
    mx = max(mx, __shfl_xor(mx, 4));
    mx = max(mx, __shfl_xor(mx, 8));

    unsigned zoff0 = (((unsigned)((SG - sg)*NN)) << 7);

    // addr-lane roles: lane (as edge id within chunk) -> row lane>>1, slot lane&1
    int aG2  = __shfl(a,  lane >> 1);
    int dgG2 = __shfl(dg, lane >> 1);

    f32x4 acc[4];
    #pragma unroll
    for (int cb = 0; cb < 4; ++cb) acc[cb] = (f32x4){0.f,0.f,0.f,0.f};

    if (mx > 0){
        int nch = (mx + 1) >> 1;              // 2 edges per row per chunk
        uint4 vA[4], vB[4];
        int ixA, ixB;
        LDIX(ixA, 0);
        LDIX(ixB, 1);
        GATH(vA, ixA, 0);
        if (nch > 1) GATH(vB, ixB, 1);
        LDIX(ixA, 2);
        LDIX(ixB, 3);
        for (int c = 0; c < nch; c += 2){
            CONSUME(vA);
            if (c + 2 < nch){ GATH(vA, ixA, c + 2); LDIX(ixA, c + 4); }
            if (c + 1 < nch){
                CONSUME(vB);
                if (c + 3 < nch){ GATH(vB, ixB, c + 3); LDIX(ixB, c + 5); }
            }
        }
    }

    // mean: scale by 1/deg of row (q*4+reg); write bf16 mean into sM overlay
    asm volatile("" ::: "memory");
    unsigned short* sMw = stg;                // shorts [0, 1152)
    float inv[4];
    #pragma unroll
    for (int reg = 0; reg < 4; ++reg){
        int d = __shfl(dg, (q << 2) | reg, 16);
        inv[reg] = (d > 0) ? rcpf((float)d) : 0.0f;
    }
    #pragma unroll
    for (int cb = 0; cb < 4; ++cb)
        #pragma unroll
        for (int reg = 0; reg < 4; ++reg)
            sMw[(q*4 + reg)*WP + cb*16 + r] = f2bf(acc[cb][reg] * inv[reg]);
    asm volatile("" ::: "memory");

    // matmul: C = mean@Wl + self@Wr
    const unsigned short* WLg = WL + (size_t)g*64*128;
    f32x4 accv[4];
    #pragma unroll
    for (int ct = 0; ct < 4; ++ct) accv[ct] = (f32x4){0.f,0.f,0.f,0.f};
    #pragma unroll
    for (int kc = 0; kc < 4; ++kc){
        bf16x8 af;
        if (kc < 2) af = *(const bf16x8*)&sMw[r*WP + kc*32 + q*8];
        else        af = *(const bf16x8*)(inbc + (((unsigned)node) << 7) + (unsigned)((kc-2)*64 + q*16));
        #pragma unroll
        for (int ct = 0; ct < 4; ++ct){
            bf16x8 bfr = *(const bf16x8*)&WLg[(ct*16 + r)*128 + kc*32 + q*8];
            accv[ct] = __builtin_amdgcn_mfma_f32_16x16x32_bf16(af, bfr, accv[ct], 0, 0, 0);
        }
    }

    // epilogue: bias + tanh -> bf16, transpose through sO overlay (reuses sM space
    // after all sM reads; same-wave in-order LDS), scatter store by nid
    asm volatile("" ::: "memory");
    unsigned short* sOw = stg;                // shorts [0, 1152), reuse after matmul
    #pragma unroll
    for (int ct = 0; ct < 4; ++ct){
        float bv = bias[g*64 + ct*16 + r];
        #pragma unroll
        for (int reg = 0; reg < 4; ++reg)
            sOw[(q*4+reg)*WP + ct*16 + r] = f2bf(tanhf_fast(accv[ct][reg] + bv));
    }
    asm volatile("" ::: "memory");
    #pragma unroll
    for (int pass = 0; pass < 2; ++pass){
        int rloc = pass*8 + (lane >> 3), chunk = lane & 7;
        int i2 = gid*16 + rloc;
        int nd = nid2[sg*NN + i2];
        uint4 v = *(const uint4*)&sOw[rloc*WP + chunk*8];
        *(uint4*)&outb[((size_t)sg*NN + nd)*D + chunk*8] = v;
    }
}

// ---------------- LSTM: col-partitioned waves; Wt read once per block; 3 barriers ----------------

__global__ __launch_bounds__(256) void lstm_kernel(const unsigned short* __restrict__ h2b,
                                                   const unsigned short* __restrict__ Wt,
                                                   const float* __restrict__ bc,
                                                   float* __restrict__ out){
    __shared__ unsigned short sH[64*WP];  // 9.2 KB, whole block's h
    int tid = threadIdx.x;
    int b0 = blockIdx.x * 64;
    int wave = tid >> 6, lane = tid & 63;
    int n0 = lane & 15, q = lane >> 4;
    int jcol = wave*16 + n0;              // output col j in [0,64)

    float bb[4];
    #pragma unroll
    for (int T = 0; T < 4; ++T) bb[T] = bc[T*64 + jcol];

    float c[4][4];  // [rt][reg]
    #pragma unroll
    for (int rt = 0; rt < 4; ++rt)
        #pragma unroll
        for (int reg = 0; reg < 4; ++reg) c[rt][reg] = 0.0f;

    int s_[4], n_[4];
    #pragma unroll
    for (int rt = 0; rt < 4; ++rt){
        int b = b0 + rt*16 + n0;
        s_[rt] = b / NN; n_[rt] = b - s_[rt]*NN;
    }

    #pragma unroll
    for (int t = 0; t < G; ++t){
        f32x4 accv[4][4];  // [rt][T]
        #pragma unroll
        for (int rt = 0; rt < 4; ++rt)
            #pragma unroll
            for (int T = 0; T < 4; ++T) accv[rt][T] = (f32x4){0.f,0.f,0.f,0.f};

        int nkc = (t == 0) ? 2 : 4;
        #pragma unroll
        for (int kc = 0; kc < 4; ++kc){
            if (kc >= nkc) break;
            bf16x8 af[4];
            #pragma unroll
            for (int rt = 0; rt < 4; ++rt){
                if (kc < 2) af[rt] = *(const bf16x8*)&h2b[((size_t)(s_[rt]*G + t)*NN + n_[rt])*D + kc*32 + q*8];
                else        af[rt] = *(const bf16x8*)&sH[(rt*16 + n0)*WP + (kc-2)*32 + q*8];
            }
            #pragma unroll
            for (int T = 0; T < 4; ++T){
                int ct = T*4 + wave;
                bf16x8 bfr = *(const bf16x8*)&Wt[(ct*16 + n0)*128 + kc*32 + q*8];
                #pragma unroll
                for (int rt = 0; rt < 4; ++rt)
                    accv[rt][T] = __builtin_amdgcn_mfma_f32_16x16x32_bf16(af[rt], bfr, accv[rt][T], 0, 0, 0);
            }
        }
        if (t > 0) __syncthreads();   // WAR: all sH reads done before overwrite

        #pragma unroll
        for (int rt = 0; rt < 4; ++rt){
            #pragma unroll
            for (int reg = 0; reg < 4; ++reg){
                float ig = sigmf(accv[rt][0][reg] + bb[0]);
                float fg = sigmf(accv[rt][1][reg] + bb[1]);
                float gg = tanhf_fast(accv[rt][2][reg] + bb[2]);
                float og = sigmf(accv[rt][3][reg] + bb[3]);
                float cn = fg*c[rt][reg] + ig*gg;
                c[rt][reg] = cn;
                float hv = og * tanhf_fast(cn);
                int row = rt*16 + q*4 + reg;
                if (t < G-1) sH[row*WP + jcol] = f2bf(hv);
                else         out[(size_t)(b0 + row)*D + jcol] = hv;
            }
        }
        if (t < G-1) __syncthreads(); // RAW: h visible before next t's reads
    }
}

// ---------------- host ----------------

extern "C" void kernel_launch(void* const* d_in, const int* in_sizes, int n_in,
                              void* d_out, int out_size, void* d_ws, size_t ws_size,
                              hipStream_t stream) {
    const float* x   = (const float*)d_in[0];
    const int*   ei  = (const int*)  d_in[1];
    const float* W1l = (const float*)d_in[2];
    const float* W1r = (const float*)d_in[3];
    const float* b1  = (const float*)d_in[4];
    const float* W2l = (const float*)d_in[5];
    const float* W2r = (const float*)d_in[6];
    const float* b2  = (const float*)d_in[7];
    const float* Wih = (const float*)d_in[8];
    const float* Whh = (const float*)d_in[9];
    const float* bih = (const float*)d_in[10];
    const float* bhh = (const float*)d_in[11];
    float* out = (float*)d_out;

    char* ws = (char*)d_ws;
    size_t cur = 0;
    auto alloc = [&](size_t bytes)->void*{
        cur = (cur + 255) & ~(size_t)255;
        void* p = ws + cur; cur += bytes; return p;
    };
    int*   bkt  = (int*)alloc((size_t)SG*RGS*BCAP*4);   // buckets, then CSR in place
    int*   bcur = (int*)alloc((size_t)SG*RGS*4);
    int*   off2 = (int*)alloc((size_t)SG*NN*4);
    int*   deg2 = (int*)alloc((size_t)SG*NN*4);
    int*   nid2 = (int*)alloc((size_t)SG*NN*4);
    int*   offU = (int*)alloc((size_t)SG*NN*4);
    unsigned short* xb  = (unsigned short*)alloc(((size_t)SG*NN + 1)*D*2);  // +1 zero row
    unsigned short* h1b = (unsigned short*)alloc(((size_t)SG*NN + 1)*D*2);  // +1 zero row
    unsigned short* h2b = (unsigned short*)alloc((size_t)SG*NN*D*2);
    unsigned short* WL1 = (unsigned short*)alloc((size_t)G*64*128*2);
    unsigned short* WL2 = (unsigned short*)alloc((size_t)G*64*128*2);
    unsigned short* Wt  = (unsigned short*)alloc((size_t)256*128*2);
    float* bc   = (float*)alloc((size_t)256*4);
    (void)ws_size; (void)in_sizes; (void)n_in; (void)out_size;

    (void)hipMemsetAsync(bcur, 0, (size_t)SG*RGS*4, stream);
    (void)hipMemsetAsync(xb  + (size_t)SG*NN*D, 0, (size_t)D*2, stream);  // shared zero row
    (void)hipMemsetAsync(h1b + (size_t)SG*NN*D, 0, (size_t)D*2, stream);  // shared zero row

    convert_kernel<<<(SG*NN*16 + 255)/256, 256, 0, stream>>>(x, xb);
    binA_kernel  <<<dim3(CHUNKA, SG), 256, 0, stream>>>(ei, bcur, bkt);
    buildB_kernel<<<SG*RGS, 256, 0, stream>>>(bkt, bcur, off2, deg2, nid2, offU);
    wprep2_kernel<<<321, 256, 0, stream>>>(W1l, W1r, W2l, W2r, Wih, Whh, bih, bhh,
                                           WL1, WL2, Wt, bc);

    layer_kernel<<<LT2, 64, 0, stream>>>(xb,  off2, deg2, nid2, bkt, WL1, b1, h1b);
    layer_kernel<<<LT2, 64, 0, stream>>>(h1b, off2, deg2, nid2, bkt, WL2, b2, h2b);

    lstm_kernel <<<(S*NN)/64, 256, 0, stream>>>(h2b, Wt, bc, out);
}